// Round 1
// baseline (38.880 us; speedup 1.0000x reference)
//
#include <hip/hip_runtime.h>

// LSP -> LPC, LPC_ORDER = 24, rows of 25 fp32: [K, ang0..ang23]
// P roots: ang[1::2] (w idx 2,4,..,24); Q roots: ang[0::2] (w idx 1,3,..,23)
// Each conjugate pair => real quadratic (x^2 - 2cos(th) x + 1).
// Product of palindromic quadratics is palindromic: keep coeffs 0..12 only.

static constexpr int NC  = 25;
static constexpr int RPB = 256;                       // rows per block
static constexpr int FPB = NC * RPB;                  // 6400 floats per block
static constexpr int V4  = FPB / 4;                   // 1600 float4
static constexpr int TAIL = V4 - 6 * RPB;             // 64

__global__ __launch_bounds__(256)
void lsp2lpc_kernel(const float* __restrict__ in, float* __restrict__ out) {
    __shared__ float lds[FPB];                         // 25.6 KB
    const int tid = threadIdx.x;
    const size_t base = (size_t)blockIdx.x * FPB;      // block offset: 25600 B, 16B-aligned

    // coalesced float4 global -> LDS staging
    const float4* gin  = reinterpret_cast<const float4*>(in + base);
    float4*       lds4 = reinterpret_cast<float4*>(lds);
#pragma unroll
    for (int i = 0; i < 6; ++i)
        lds4[tid + i * RPB] = gin[tid + i * RPB];
    if (tid < TAIL)
        lds4[tid + 6 * RPB] = gin[tid + 6 * RPB];
    __syncthreads();

    // per-thread row (stride 25 = odd -> 2 lanes/bank, conflict-free)
    const float* row = &lds[tid * NC];
    const float K = row[0];
    float cp[12], cq[12];
#pragma unroll
    for (int m = 0; m < 12; ++m) {
        cq[m] = __cosf(row[1 + 2 * m]);   // Q: ang indices 0,2,..,22
        cp[m] = __cosf(row[2 + 2 * m]);   // P: ang indices 1,3,..,23
    }

    // palindromic lower halves of P, Q (degree 24 -> coeffs 0..12)
    float P[13], Q[13];
#pragma unroll
    for (int k = 0; k < 13; ++k) { P[k] = 0.f; Q[k] = 0.f; }
    P[0] = 1.f; Q[0] = 1.f;

#pragma unroll
    for (int m = 0; m < 12; ++m) {
        const float tp = -2.f * cp[m];
        const float tq = -2.f * cq[m];
        const int kmax = (2 * m + 2 < 12) ? (2 * m + 2) : 12;
        // in-place descending convolution with [1, t, 1]
#pragma unroll
        for (int k = 12; k >= 0; --k) {
            if (k > kmax) continue;               // compile-time pruned
            const float p1 = (k >= 1) ? P[k - 1] : 0.f;
            const float p2 = (k >= 2) ? P[k - 2] : 0.f;
            P[k] = fmaf(tp, p1, P[k]) + p2;
            const float q1 = (k >= 1) ? Q[k - 1] : 0.f;
            const float q2 = (k >= 2) ? Q[k - 2] : 0.f;
            Q[k] = fmaf(tq, q1, Q[k]) + q2;
        }
    }
    __syncthreads();   // all LDS input reads done; safe to overwrite buffer

    // epilogue: a[k] = 0.5*((Pf[k+1]-Pf[k]) + (Qf[k]+Qf[k+1])), Pf[j] = j<=12 ? P[j] : P[24-j]
    float* orow = &lds[tid * NC];
    orow[0] = K;
#pragma unroll
    for (int k = 0; k < 24; ++k) {
        const int i0 = (k     <= 12) ? k       : 24 - k;
        const int i1 = (k + 1 <= 12) ? (k + 1) : 24 - (k + 1);
        const float pc = P[i1] - P[i0];
        const float qc = Q[i0] + Q[i1];
        orow[1 + k] = 0.5f * (pc + qc);
    }
    __syncthreads();

    // coalesced float4 LDS -> global store
    float4* gout = reinterpret_cast<float4*>(out + base);
#pragma unroll
    for (int i = 0; i < 6; ++i)
        gout[tid + i * RPB] = lds4[tid + i * RPB];
    if (tid < TAIL)
        gout[tid + 6 * RPB] = lds4[tid + 6 * RPB];
}

extern "C" void kernel_launch(void* const* d_in, const int* in_sizes, int n_in,
                              void* d_out, int out_size, void* d_ws, size_t ws_size,
                              hipStream_t stream) {
    const float* in  = (const float*)d_in[0];
    float*       out = (float*)d_out;
    const int nrows   = in_sizes[0] / NC;   // 512*2048 = 1048576
    const int nblocks = nrows / RPB;        // 4096 (exact)
    lsp2lpc_kernel<<<nblocks, RPB, 0, stream>>>(in, out);
}